// Round 1
// baseline (447.025 us; speedup 1.0000x reference)
//
#include <hip/hip_runtime.h>
#include <hip/hip_bf16.h>
#include <cstdint>
#include <math.h>

#define DMODEL 1024
#define SEQ    4096
#define NHEAD  16
#define DK     64

typedef __attribute__((ext_vector_type(8))) short bf16x8;   // 8 bf16 = 4 VGPRs
typedef __attribute__((ext_vector_type(4))) float f32x4;
typedef unsigned short u16;

__device__ __forceinline__ u16 f2bf(float f) {
    union { float f; unsigned int u; } v; v.f = f;
    unsigned int u = v.u;
    u += 0x7FFFu + ((u >> 16) & 1u);   // round-to-nearest-even
    return (u16)(u >> 16);
}
__device__ __forceinline__ float bf2f(u16 h) {
    union { unsigned int u; float f; } v; v.u = ((unsigned int)h) << 16;
    return v.f;
}
__device__ __forceinline__ unsigned int pk_bf16(float a, float b) {
    union { __hip_bfloat162 h; unsigned int u; } v;
    v.h = __float22bfloat162_rn(make_float2(a, b));
    return v.u;
}
// raw v_exp_f32 = 2^x (Q is pre-scaled by 1/8 * log2(e) so this computes e^s)
__device__ __forceinline__ float fast_exp2(float x) {
    float r; asm("v_exp_f32 %0, %1" : "=v"(r) : "v"(x)); return r;
}

// Fallback marker if ws_size too small (diagnostic).
__global__ __launch_bounds__(256) void fallback_marker(float* __restrict__ out, int n) {
    int i = blockIdx.x * 256 + threadIdx.x;
    if (i < n) out[i] = (i == 0) ? 12345.0f : 0.0f;
}

// ---------------------------------------------------------------------------
// fp32 -> (hi, lo) bf16 split, elementwise (float4 granularity).
// ---------------------------------------------------------------------------
__device__ __forceinline__ void split4_store(const float* __restrict__ in,
                                             u16* __restrict__ hi,
                                             u16* __restrict__ lo, int i) {
    float4 v = ((const float4*)in)[i];
    u16 h0 = f2bf(v.x), h1 = f2bf(v.y), h2 = f2bf(v.z), h3 = f2bf(v.w);
    ushort4 hv; hv.x = h0; hv.y = h1; hv.z = h2; hv.w = h3;
    ushort4 lv;
    lv.x = f2bf(v.x - bf2f(h0)); lv.y = f2bf(v.y - bf2f(h1));
    lv.z = f2bf(v.z - bf2f(h2)); lv.w = f2bf(v.w - bf2f(h3));
    ((ushort4*)hi)[i] = hv;
    ((ushort4*)lo)[i] = lv;
}

__global__ __launch_bounds__(256) void split_kernel(const float* __restrict__ in,
                                                    u16* __restrict__ hi,
                                                    u16* __restrict__ lo, int n4) {
    int i = blockIdx.x * 256 + threadIdx.x;
    if (i < n4) split4_store(in, hi, lo, i);
}

// Activation (y=0) + weight (y=1) split fused into one launch.
__global__ __launch_bounds__(256) void split_pair(const float* __restrict__ a_in,
                                                  u16* __restrict__ a_hi,
                                                  u16* __restrict__ a_lo, int a_n4,
                                                  const float* __restrict__ w_in,
                                                  u16* __restrict__ w_hi,
                                                  u16* __restrict__ w_lo, int w_n4) {
    int i = blockIdx.x * 256 + threadIdx.x;
    if (blockIdx.y == 0) {
        if (i < a_n4) split4_store(a_in, a_hi, a_lo, i);
    } else {
        if (i < w_n4) split4_store(w_in, w_hi, w_lo, i);
    }
}

// ---------------------------------------------------------------------------
// hi/lo-split MFMA GEMM core v3: 64x64 tile, 4 waves, each wave owns
// 16 rows (1 m-frag) x 64 cols. Doubles grid (1024 blocks = 4/CU, 16
// waves/CU) vs v2's 512 blocks = 2/CU. Per-output hi*hi,hi*lo,lo*hi
// accumulation order identical to v2.
// ---------------------------------------------------------------------------
__device__ __forceinline__ void gemm_core_hl3(const u16* __restrict__ aHi,
                                              const u16* __restrict__ aLo,
                                              const u16* __restrict__ bHi,
                                              const u16* __restrict__ bLo,
                                              int bm, int bn,
                                              f32x4 (&acc)[4]) {
    __shared__ u16 sAh[64 * 72], sAl[64 * 72];   // 9 KB each
    __shared__ u16 sBh[64 * 72], sBl[64 * 72];   // 9 KB each  (36 KB total)

    const int tid  = threadIdx.x;
    const int wave = tid >> 6;
    const int lane = tid & 63;
    const int quad = lane >> 4;
    const int l15  = lane & 15;
    const int srow = tid >> 2;          // 0..63
    const int scol = (tid & 3) * 16;    // 0,16,32,48

    const u16* pAh = aHi + (size_t)(bm + srow) * DMODEL + scol;
    const u16* pAl = aLo + (size_t)(bm + srow) * DMODEL + scol;
    const u16* pBh = bHi + (size_t)(bn + srow) * DMODEL + scol;
    const u16* pBl = bLo + (size_t)(bn + srow) * DMODEL + scol;

    for (int k0 = 0; k0 < DMODEL; k0 += 64) {
        uint4 ah0 = *(const uint4*)(pAh + k0);
        uint4 ah1 = *(const uint4*)(pAh + k0 + 8);
        uint4 al0 = *(const uint4*)(pAl + k0);
        uint4 al1 = *(const uint4*)(pAl + k0 + 8);
        uint4 bh0 = *(const uint4*)(pBh + k0);
        uint4 bh1 = *(const uint4*)(pBh + k0 + 8);
        uint4 bl0 = *(const uint4*)(pBl + k0);
        uint4 bl1 = *(const uint4*)(pBl + k0 + 8);

        __syncthreads();
        *(uint4*)&sAh[srow * 72 + scol]     = ah0;
        *(uint4*)&sAh[srow * 72 + scol + 8] = ah1;
        *(uint4*)&sAl[srow * 72 + scol]     = al0;
        *(uint4*)&sAl[srow * 72 + scol + 8] = al1;
        *(uint4*)&sBh[srow * 72 + scol]     = bh0;
        *(uint4*)&sBh[srow * 72 + scol + 8] = bh1;
        *(uint4*)&sBl[srow * 72 + scol]     = bl0;
        *(uint4*)&sBl[srow * 72 + scol + 8] = bl1;
        __syncthreads();

#pragma unroll
        for (int c = 0; c < 2; c++) {
            const int aoff = (wave * 16 + l15) * 72 + c * 32 + quad * 8;
            bf16x8 ah = *(const bf16x8*)&sAh[aoff];
            bf16x8 al = *(const bf16x8*)&sAl[aoff];
#pragma unroll
            for (int nt = 0; nt < 4; nt++) {
                const int boff = (nt * 16 + l15) * 72 + c * 32 + quad * 8;
                bf16x8 bhf = *(const bf16x8*)&sBh[boff];
                bf16x8 blf = *(const bf16x8*)&sBl[boff];
                acc[nt] = __builtin_amdgcn_mfma_f32_16x16x32_bf16(ah, bhf, acc[nt], 0, 0, 0);
                acc[nt] = __builtin_amdgcn_mfma_f32_16x16x32_bf16(ah, blf, acc[nt], 0, 0, 0);
                acc[nt] = __builtin_amdgcn_mfma_f32_16x16x32_bf16(al, bhf, acc[nt], 0, 0, 0);
            }
        }
    }
}

// XCD-aware bijective swizzle of a 2D grid (nwg must be divisible by 8;
// all grids here are 1024). Consecutive 128-block chunks land on one XCD.
__device__ __forceinline__ int swz_block_id() {
    const int nwg = gridDim.x * gridDim.y;
    const int lin = blockIdx.y * gridDim.x + blockIdx.x;
    return (lin & 7) * (nwg >> 3) + (lin >> 3);
}

__global__ __launch_bounds__(256) void proj_hl_bf(const u16* __restrict__ aHi,
                                                  const u16* __restrict__ aLo,
                                                  const u16* __restrict__ bHi,
                                                  const u16* __restrict__ bLo,
                                                  u16* __restrict__ C,
                                                  int ldc, float scale) {
    const int swz = swz_block_id();
    const int bm = (swz % gridDim.x) * 64;
    const int bn = (swz / gridDim.x) * 64;
    f32x4 acc[4] = {};
    gemm_core_hl3(aHi, aLo, bHi, bLo, bm, bn, acc);
    const int lane = threadIdx.x & 63;
    const int wave = threadIdx.x >> 6;
    const int quad = lane >> 4;
    const int l15  = lane & 15;
#pragma unroll
    for (int nt = 0; nt < 4; nt++) {
        int col = bn + nt * 16 + l15;
#pragma unroll
        for (int r = 0; r < 4; r++) {
            int row = bm + wave * 16 + quad * 4 + r;
            C[(size_t)row * ldc + col] = f2bf(acc[nt][r] * scale);
        }
    }
}

__global__ __launch_bounds__(256) void proj_hl_f32(const u16* __restrict__ aHi,
                                                   const u16* __restrict__ aLo,
                                                   const u16* __restrict__ bHi,
                                                   const u16* __restrict__ bLo,
                                                   float* __restrict__ C) {
    const int swz = swz_block_id();
    const int bm = (swz % gridDim.x) * 64;
    const int bn = (swz / gridDim.x) * 64;
    f32x4 acc[4] = {};
    gemm_core_hl3(aHi, aLo, bHi, bLo, bm, bn, acc);
    const int lane = threadIdx.x & 63;
    const int wave = threadIdx.x >> 6;
    const int quad = lane >> 4;
    const int l15  = lane & 15;
#pragma unroll
    for (int nt = 0; nt < 4; nt++) {
        int col = bn + nt * 16 + l15;
#pragma unroll
        for (int r = 0; r < 4; r++) {
            int row = bm + wave * 16 + quad * 4 + r;
            C[(size_t)row * DMODEL + col] = acc[nt][r];
        }
    }
}

// ---------------------------------------------------------------------------
// MFMA flash attention v3: wave owns 16 q-rows (vs v2's 32). Grid doubles
// to (64, 16) = 1024 blocks -> 4 blocks/CU, 16 waves/CU, 4 independent
// barrier domains per CU. XCD swizzle keeps each head's K/V in one XCD's L2.
// Softmax: Q pre-scaled by (1/8)*log2(e); P = v_exp_f32(s) = e^{s_orig}.
// ---------------------------------------------------------------------------
#define PST 68   // sP row stride (u16)

__global__ __launch_bounds__(256) void attn_mfma(const u16* __restrict__ Q,
                                                 const u16* __restrict__ K,
                                                 const u16* __restrict__ Vt,
                                                 u16* __restrict__ AOh,
                                                 u16* __restrict__ AOl) {
    __shared__ u16 sK[64 * 72];          // K tile [key][d]      9 KB
    __shared__ u16 sV[64 * 72];          // V tile [d][key]      9 KB
    __shared__ u16 sP[4 * 16 * PST];     // per-wave P [16][key] 8.5 KB

    const int swz  = swz_block_id();     // grid (64,16): 1024 blocks
    const int head = swz >> 6;           // 0..15; XCD chunk = 2 whole heads
    const int q0   = (swz & 63) * 64;
    const int tid  = threadIdx.x;
    const int wave = tid >> 6;
    const int lane = tid & 63;
    const int quad = lane >> 4;
    const int l15  = lane & 15;
    const int srow = tid >> 2;           // 0..63
    const int scol = (tid & 3) * 16;     // 0,16,32,48

    bf16x8 qf0, qf1;
    {
        const u16* qb = Q + (size_t)(q0 + wave * 16 + l15) * DMODEL + head * DK;
        qf0 = *(const bf16x8*)(qb + quad * 8);
        qf1 = *(const bf16x8*)(qb + 32 + quad * 8);
    }

    f32x4 oacc[4] = {};
    float l_part[4] = {};

    const u16* Kst = K  + (size_t)srow * DMODEL + head * DK + scol;
    const u16* Vst = Vt + (size_t)(head * DK + srow) * SEQ + scol;
    u16* sPw = sP + wave * 16 * PST;

    for (int k0 = 0; k0 < SEQ; k0 += 64) {
        uint4 kv0 = *(const uint4*)(Kst + (size_t)k0 * DMODEL);
        uint4 kv1 = *(const uint4*)(Kst + (size_t)k0 * DMODEL + 8);
        uint4 vv0 = *(const uint4*)(Vst + k0);
        uint4 vv1 = *(const uint4*)(Vst + k0 + 8);
        __syncthreads();
        *(uint4*)&sK[srow * 72 + scol]     = kv0;
        *(uint4*)&sK[srow * 72 + scol + 8] = kv1;
        *(uint4*)&sV[srow * 72 + scol]     = vv0;
        *(uint4*)&sV[srow * 72 + scol + 8] = vv1;
        __syncthreads();

        f32x4 s[4] = {};
#pragma unroll
        for (int nt = 0; nt < 4; nt++) {
            bf16x8 b0 = *(const bf16x8*)&sK[(nt * 16 + l15) * 72 + quad * 8];
            bf16x8 b1 = *(const bf16x8*)&sK[(nt * 16 + l15) * 72 + 32 + quad * 8];
            s[nt] = __builtin_amdgcn_mfma_f32_16x16x32_bf16(qf0, b0, s[nt], 0, 0, 0);
            s[nt] = __builtin_amdgcn_mfma_f32_16x16x32_bf16(qf1, b1, s[nt], 0, 0, 0);
        }

#pragma unroll
        for (int nt = 0; nt < 4; nt++) {
            float p0 = fast_exp2(s[nt][0]);
            float p1 = fast_exp2(s[nt][1]);
            float p2 = fast_exp2(s[nt][2]);
            float p3 = fast_exp2(s[nt][3]);
            l_part[0] += p0; l_part[1] += p1;
            l_part[2] += p2; l_part[3] += p3;
            unsigned int u01 = pk_bf16(p0, p1);
            unsigned int u23 = pk_bf16(p2, p3);
            const int rb   = quad * 4;
            const int colo = nt * 16 + l15;
            sPw[(rb + 0) * PST + colo] = (u16)(u01 & 0xFFFFu);
            sPw[(rb + 1) * PST + colo] = (u16)(u01 >> 16);
            sPw[(rb + 2) * PST + colo] = (u16)(u23 & 0xFFFFu);
            sPw[(rb + 3) * PST + colo] = (u16)(u23 >> 16);
        }

#pragma unroll
        for (int c = 0; c < 2; c++) {
            bf16x8 pf = *(const bf16x8*)&sPw[l15 * PST + c * 32 + quad * 8];
#pragma unroll
            for (int nt = 0; nt < 4; nt++) {
                bf16x8 vf = *(const bf16x8*)&sV[(nt * 16 + l15) * 72 + c * 32 + quad * 8];
                oacc[nt] = __builtin_amdgcn_mfma_f32_16x16x32_bf16(pf, vf, oacc[nt], 0, 0, 0);
            }
        }
    }

    float l_i[4];
#pragma unroll
    for (int r = 0; r < 4; r++) {
        float l = l_part[r];
        l += __shfl_xor(l, 1);
        l += __shfl_xor(l, 2);
        l += __shfl_xor(l, 4);
        l += __shfl_xor(l, 8);
        l_i[r] = l;
    }
#pragma unroll
    for (int nt = 0; nt < 4; nt++) {
        int col = head * DK + nt * 16 + l15;
#pragma unroll
        for (int r = 0; r < 4; r++) {
            int row = q0 + wave * 16 + quad * 4 + r;
            float o = oacc[nt][r] / l_i[r];
            u16 h = f2bf(o);
            AOh[(size_t)row * DMODEL + col] = h;
            AOl[(size_t)row * DMODEL + col] = f2bf(o - bf2f(h));
        }
    }
}

// ---------------------------------------------------------------------------
extern "C" void kernel_launch(void* const* d_in, const int* in_sizes, int n_in,
                              void* d_out, int out_size, void* d_ws, size_t ws_size,
                              hipStream_t stream) {
    const float* query = (const float*)d_in[0];
    const float* key_t = (const float*)d_in[1];
    const float* value = (const float*)d_in[2];
    const float* wq    = (const float*)d_in[3];
    const float* wk    = (const float*)d_in[4];
    const float* wv    = (const float*)d_in[5];
    const float* wo    = (const float*)d_in[6];
    float* out = (float*)d_out;

    const size_t ACT_N = (size_t)SEQ * DMODEL;
    const size_t W_N   = (size_t)DMODEL * DMODEL;
    const size_t NEED  = 4 * ACT_N * sizeof(float);   // 64 MB (verified available)

    if (d_ws == nullptr || ws_size < NEED) {
        fallback_marker<<<dim3((out_size + 255) / 256), dim3(256), 0, stream>>>(out, out_size);
        return;
    }

    u16* ACT_HI = (u16*)d_ws;          // 8 MB  (phased)
    u16* ACT_LO = ACT_HI + ACT_N;      // 8 MB
    u16* W_HI   = ACT_LO + ACT_N;      // 2 MB  (phased)
    u16* W_LO   = W_HI + W_N;          // 2 MB
    u16* Qb     = W_LO + W_N;          // 8 MB  bf16 Q (pre-scaled 1/8*log2e)
    u16* Kb     = Qb + ACT_N;          // 8 MB  bf16 K
    u16* Vt     = Kb + ACT_N;          // 8 MB  bf16 V^T [DMODEL][SEQ]
    u16* AO_HI  = Vt + ACT_N;          // 8 MB
    u16* AO_LO  = AO_HI + ACT_N;       // 8 MB

    const int ACT4 = (int)(ACT_N / 4);
    const int W4   = (int)(W_N / 4);
    dim3 blk(256);
    dim3 pairg((ACT4 + 255) / 256, 2);
    dim3 wg((W4 + 255) / 256);

    const float QSCALE = 0.125f * 1.44269504f;   // 1/sqrt(dk) * log2(e)

    split_pair<<<pairg, blk, 0, stream>>>(query, ACT_HI, ACT_LO, ACT4, wq, W_HI, W_LO, W4);
    proj_hl_bf<<<dim3(SEQ / 64, DMODEL / 64), blk, 0, stream>>>(
        ACT_HI, ACT_LO, W_HI, W_LO, Qb, DMODEL, QSCALE);

    split_pair<<<pairg, blk, 0, stream>>>(key_t, ACT_HI, ACT_LO, ACT4, wk, W_HI, W_LO, W4);
    proj_hl_bf<<<dim3(SEQ / 64, DMODEL / 64), blk, 0, stream>>>(
        ACT_HI, ACT_LO, W_HI, W_LO, Kb, DMODEL, 1.0f);

    split_pair<<<pairg, blk, 0, stream>>>(value, ACT_HI, ACT_LO, ACT4, wv, W_HI, W_LO, W4);
    proj_hl_bf<<<dim3(DMODEL / 64, SEQ / 64), blk, 0, stream>>>(
        W_HI, W_LO, ACT_HI, ACT_LO, Vt, SEQ, 1.0f);

    attn_mfma<<<dim3(SEQ / 64, NHEAD), blk, 0, stream>>>(Qb, Kb, Vt, AO_HI, AO_LO);

    split_kernel<<<wg, blk, 0, stream>>>(wo, W_HI, W_LO, W4);
    proj_hl_f32<<<dim3(SEQ / 64, DMODEL / 64), blk, 0, stream>>>(
        AO_HI, AO_LO, W_HI, W_LO, out);
}

// Round 2
// 395.722 us; speedup vs baseline: 1.1296x; 1.1296x over previous
//
#include <hip/hip_runtime.h>
#include <hip/hip_bf16.h>
#include <cstdint>
#include <math.h>

#define DMODEL 1024
#define SEQ    4096
#define NHEAD  16
#define DK     64

typedef __attribute__((ext_vector_type(8))) short bf16x8;   // 8 bf16 = 4 VGPRs
typedef __attribute__((ext_vector_type(4))) float f32x4;
typedef unsigned short u16;

__device__ __forceinline__ u16 f2bf(float f) {
    union { float f; unsigned int u; } v; v.f = f;
    unsigned int u = v.u;
    u += 0x7FFFu + ((u >> 16) & 1u);   // round-to-nearest-even
    return (u16)(u >> 16);
}
__device__ __forceinline__ float bf2f(u16 h) {
    union { unsigned int u; float f; } v; v.u = ((unsigned int)h) << 16;
    return v.f;
}
__device__ __forceinline__ unsigned int pk_bf16(float a, float b) {
    union { __hip_bfloat162 h; unsigned int u; } v;
    v.h = __float22bfloat162_rn(make_float2(a, b));
    return v.u;
}
// raw v_exp_f32 = 2^x (Q is pre-scaled by 1/8 * log2(e) so this computes e^s)
__device__ __forceinline__ float fast_exp2(float x) {
    float r; asm("v_exp_f32 %0, %1" : "=v"(r) : "v"(x)); return r;
}

// Fallback marker if ws_size too small (diagnostic).
__global__ __launch_bounds__(256) void fallback_marker(float* __restrict__ out, int n) {
    int i = blockIdx.x * 256 + threadIdx.x;
    if (i < n) out[i] = (i == 0) ? 12345.0f : 0.0f;
}

// ---------------------------------------------------------------------------
// fp32 -> (hi, lo) bf16 split, elementwise (float4 granularity).
// ---------------------------------------------------------------------------
__device__ __forceinline__ void split4_store(const float* __restrict__ in,
                                             u16* __restrict__ hi,
                                             u16* __restrict__ lo, int i) {
    float4 v = ((const float4*)in)[i];
    u16 h0 = f2bf(v.x), h1 = f2bf(v.y), h2 = f2bf(v.z), h3 = f2bf(v.w);
    ushort4 hv; hv.x = h0; hv.y = h1; hv.z = h2; hv.w = h3;
    ushort4 lv;
    lv.x = f2bf(v.x - bf2f(h0)); lv.y = f2bf(v.y - bf2f(h1));
    lv.z = f2bf(v.z - bf2f(h2)); lv.w = f2bf(v.w - bf2f(h3));
    ((ushort4*)hi)[i] = hv;
    ((ushort4*)lo)[i] = lv;
}

__global__ __launch_bounds__(256) void split_kernel(const float* __restrict__ in,
                                                    u16* __restrict__ hi,
                                                    u16* __restrict__ lo, int n4) {
    int i = blockIdx.x * 256 + threadIdx.x;
    if (i < n4) split4_store(in, hi, lo, i);
}

// Activation (y=0) + weight (y=1) split fused into one launch.
__global__ __launch_bounds__(256) void split_pair(const float* __restrict__ a_in,
                                                  u16* __restrict__ a_hi,
                                                  u16* __restrict__ a_lo, int a_n4,
                                                  const float* __restrict__ w_in,
                                                  u16* __restrict__ w_hi,
                                                  u16* __restrict__ w_lo, int w_n4) {
    int i = blockIdx.x * 256 + threadIdx.x;
    if (blockIdx.y == 0) {
        if (i < a_n4) split4_store(a_in, a_hi, a_lo, i);
    } else {
        if (i < w_n4) split4_store(w_in, w_hi, w_lo, i);
    }
}

// ---------------------------------------------------------------------------
// hi/lo-split MFMA GEMM core v2 (round-0 proven, 401.8us baseline): 128x64
// tile, wave owns 32 rows (2 m-frags) x 64 cols. Per-output accumulation
// order fixed => bit-identical results across rounds.
// ---------------------------------------------------------------------------
__device__ __forceinline__ void gemm_core_hl2(const u16* __restrict__ aHi,
                                              const u16* __restrict__ aLo,
                                              const u16* __restrict__ bHi,
                                              const u16* __restrict__ bLo,
                                              int bm, int bn,
                                              f32x4 (&acc)[2][4]) {
    __shared__ u16 sAh[128 * 72], sAl[128 * 72];   // 18 KB each
    __shared__ u16 sBh[64 * 72],  sBl[64 * 72];    // 9 KB each  (54 KB total)

    const int tid  = threadIdx.x;
    const int wave = tid >> 6;
    const int lane = tid & 63;
    const int quad = lane >> 4;
    const int l15  = lane & 15;
    const int srow = tid >> 2;          // 0..63
    const int scol = (tid & 3) * 16;    // 0,16,32,48

    const u16* pAh0 = aHi + (size_t)(bm + srow) * DMODEL + scol;
    const u16* pAh1 = aHi + (size_t)(bm + 64 + srow) * DMODEL + scol;
    const u16* pAl0 = aLo + (size_t)(bm + srow) * DMODEL + scol;
    const u16* pAl1 = aLo + (size_t)(bm + 64 + srow) * DMODEL + scol;
    const u16* pBh  = bHi + (size_t)(bn + srow) * DMODEL + scol;
    const u16* pBl  = bLo + (size_t)(bn + srow) * DMODEL + scol;

    for (int k0 = 0; k0 < DMODEL; k0 += 64) {
        uint4 ah00 = *(const uint4*)(pAh0 + k0);
        uint4 ah01 = *(const uint4*)(pAh0 + k0 + 8);
        uint4 ah10 = *(const uint4*)(pAh1 + k0);
        uint4 ah11 = *(const uint4*)(pAh1 + k0 + 8);
        uint4 al00 = *(const uint4*)(pAl0 + k0);
        uint4 al01 = *(const uint4*)(pAl0 + k0 + 8);
        uint4 al10 = *(const uint4*)(pAl1 + k0);
        uint4 al11 = *(const uint4*)(pAl1 + k0 + 8);
        uint4 bh0  = *(const uint4*)(pBh + k0);
        uint4 bh1  = *(const uint4*)(pBh + k0 + 8);
        uint4 bl0  = *(const uint4*)(pBl + k0);
        uint4 bl1  = *(const uint4*)(pBl + k0 + 8);

        __syncthreads();
        *(uint4*)&sAh[srow * 72 + scol]            = ah00;
        *(uint4*)&sAh[srow * 72 + scol + 8]        = ah01;
        *(uint4*)&sAh[(64 + srow) * 72 + scol]     = ah10;
        *(uint4*)&sAh[(64 + srow) * 72 + scol + 8] = ah11;
        *(uint4*)&sAl[srow * 72 + scol]            = al00;
        *(uint4*)&sAl[srow * 72 + scol + 8]        = al01;
        *(uint4*)&sAl[(64 + srow) * 72 + scol]     = al10;
        *(uint4*)&sAl[(64 + srow) * 72 + scol + 8] = al11;
        *(uint4*)&sBh[srow * 72 + scol]            = bh0;
        *(uint4*)&sBh[srow * 72 + scol + 8]        = bh1;
        *(uint4*)&sBl[srow * 72 + scol]            = bl0;
        *(uint4*)&sBl[srow * 72 + scol + 8]        = bl1;
        __syncthreads();

#pragma unroll
        for (int c = 0; c < 2; c++) {
            bf16x8 ah[2], al[2];
#pragma unroll
            for (int m = 0; m < 2; m++) {
                const int aoff = (wave * 32 + m * 16 + l15) * 72 + c * 32 + quad * 8;
                ah[m] = *(const bf16x8*)&sAh[aoff];
                al[m] = *(const bf16x8*)&sAl[aoff];
            }
#pragma unroll
            for (int nt = 0; nt < 4; nt++) {
                const int boff = (nt * 16 + l15) * 72 + c * 32 + quad * 8;
                bf16x8 bhf = *(const bf16x8*)&sBh[boff];
                bf16x8 blf = *(const bf16x8*)&sBl[boff];
#pragma unroll
                for (int m = 0; m < 2; m++) {
                    acc[m][nt] = __builtin_amdgcn_mfma_f32_16x16x32_bf16(ah[m], bhf, acc[m][nt], 0, 0, 0);
                    acc[m][nt] = __builtin_amdgcn_mfma_f32_16x16x32_bf16(ah[m], blf, acc[m][nt], 0, 0, 0);
                    acc[m][nt] = __builtin_amdgcn_mfma_f32_16x16x32_bf16(al[m], bhf, acc[m][nt], 0, 0, 0);
                }
            }
        }
    }
}

__global__ __launch_bounds__(256) void proj_hl_bf(const u16* __restrict__ aHi,
                                                  const u16* __restrict__ aLo,
                                                  const u16* __restrict__ bHi,
                                                  const u16* __restrict__ bLo,
                                                  u16* __restrict__ C,
                                                  int ldc, float scale) {
    const int bm = blockIdx.x * 128;
    const int bn = blockIdx.y * 64;
    f32x4 acc[2][4] = {};
    gemm_core_hl2(aHi, aLo, bHi, bLo, bm, bn, acc);
    const int lane = threadIdx.x & 63;
    const int wave = threadIdx.x >> 6;
    const int quad = lane >> 4;
    const int l15  = lane & 15;
#pragma unroll
    for (int m = 0; m < 2; m++)
#pragma unroll
        for (int nt = 0; nt < 4; nt++) {
            int col = bn + nt * 16 + l15;
#pragma unroll
            for (int r = 0; r < 4; r++) {
                int row = bm + wave * 32 + m * 16 + quad * 4 + r;
                C[(size_t)row * ldc + col] = f2bf(acc[m][nt][r] * scale);
            }
        }
}

__global__ __launch_bounds__(256) void proj_hl_f32(const u16* __restrict__ aHi,
                                                   const u16* __restrict__ aLo,
                                                   const u16* __restrict__ bHi,
                                                   const u16* __restrict__ bLo,
                                                   float* __restrict__ C) {
    const int bm = blockIdx.x * 128;
    const int bn = blockIdx.y * 64;
    f32x4 acc[2][4] = {};
    gemm_core_hl2(aHi, aLo, bHi, bLo, bm, bn, acc);
    const int lane = threadIdx.x & 63;
    const int wave = threadIdx.x >> 6;
    const int quad = lane >> 4;
    const int l15  = lane & 15;
#pragma unroll
    for (int m = 0; m < 2; m++)
#pragma unroll
        for (int nt = 0; nt < 4; nt++) {
            int col = bn + nt * 16 + l15;
#pragma unroll
            for (int r = 0; r < 4; r++) {
                int row = bm + wave * 32 + m * 16 + quad * 4 + r;
                C[(size_t)row * DMODEL + col] = acc[m][nt][r];
            }
        }
}

// ---------------------------------------------------------------------------
// MFMA flash attention v4: v2 decomposition (128 q-rows/block, wave owns 32,
// grid (32,16)=512) + DOUBLE-BUFFERED K/V tiles with ONE barrier per k-step.
// Next tile's global loads issue at iteration start (latency hides under
// QK^T/softmax/PV compute); LDS writes go to buf[cur^1]; single
// __syncthreads() orders writes vs next iteration's reads. XCD swizzle
// (512%8==0, bijective) keeps each head's K/V (1 MB) in one XCD's L2.
// Softmax: Q pre-scaled by (1/8)*log2(e); v_exp_f32(s) = e^{s_orig}.
// LDS: 2*9 + 2*9 (K,V dbuf) + 17 (P) = 54.3 KB -> 2 blocks/CU (grid-capped).
// ---------------------------------------------------------------------------
#define PST 68   // sP row stride (u16)

__global__ __launch_bounds__(256) void attn_mfma(const u16* __restrict__ Q,
                                                 const u16* __restrict__ K,
                                                 const u16* __restrict__ Vt,
                                                 u16* __restrict__ AOh,
                                                 u16* __restrict__ AOl) {
    __shared__ u16 sK[2][64 * 72];       // K tile [key][d]   9 KB x2
    __shared__ u16 sV[2][64 * 72];       // V tile [d][key]   9 KB x2
    __shared__ u16 sP[4 * 32 * PST];     // per-wave P [32][key] 17 KB

    // XCD-aware bijective swizzle: grid (32,16) = 512 blocks, chunk = 64.
    const int lin  = blockIdx.y * gridDim.x + blockIdx.x;
    const int swz  = (lin & 7) * 64 + (lin >> 3);
    const int head = swz >> 5;           // 0..15; 2 whole heads per XCD
    const int q0   = (swz & 31) * 128;

    const int tid  = threadIdx.x;
    const int wave = tid >> 6;
    const int lane = tid & 63;
    const int quad = lane >> 4;
    const int l15  = lane & 15;
    const int srow = tid >> 2;           // 0..63
    const int scol = (tid & 3) * 16;     // 0,16,32,48

    bf16x8 qf[2][2];
#pragma unroll
    for (int m = 0; m < 2; m++) {
        const u16* qb = Q + (size_t)(q0 + wave * 32 + m * 16 + l15) * DMODEL + head * DK;
        qf[m][0] = *(const bf16x8*)(qb + quad * 8);
        qf[m][1] = *(const bf16x8*)(qb + 32 + quad * 8);
    }

    f32x4 oacc[2][4] = {};
    float l_part[2][4] = {};

    const u16* Kst = K  + (size_t)srow * DMODEL + head * DK + scol;
    const u16* Vst = Vt + (size_t)(head * DK + srow) * SEQ + scol;
    u16* sPw = sP + wave * 32 * PST;

    // Prologue: stage tile 0 into buffer 0.
    {
        uint4 kv0 = *(const uint4*)(Kst);
        uint4 kv1 = *(const uint4*)(Kst + 8);
        uint4 vv0 = *(const uint4*)(Vst);
        uint4 vv1 = *(const uint4*)(Vst + 8);
        *(uint4*)&sK[0][srow * 72 + scol]     = kv0;
        *(uint4*)&sK[0][srow * 72 + scol + 8] = kv1;
        *(uint4*)&sV[0][srow * 72 + scol]     = vv0;
        *(uint4*)&sV[0][srow * 72 + scol + 8] = vv1;
    }
    __syncthreads();

    int cur = 0;
    for (int k0 = 0; k0 < SEQ; k0 += 64) {
        // Issue next tile's global loads first (hide L2 latency under compute).
        uint4 nkv0, nkv1, nvv0, nvv1;
        const bool has_next = (k0 + 64 < SEQ);
        if (has_next) {
            nkv0 = *(const uint4*)(Kst + (size_t)(k0 + 64) * DMODEL);
            nkv1 = *(const uint4*)(Kst + (size_t)(k0 + 64) * DMODEL + 8);
            nvv0 = *(const uint4*)(Vst + k0 + 64);
            nvv1 = *(const uint4*)(Vst + k0 + 64 + 8);
        }

        // --- QK^T from sK[cur] ---
        f32x4 s[2][4] = {};
#pragma unroll
        for (int nt = 0; nt < 4; nt++) {
            bf16x8 b0 = *(const bf16x8*)&sK[cur][(nt * 16 + l15) * 72 + quad * 8];
            bf16x8 b1 = *(const bf16x8*)&sK[cur][(nt * 16 + l15) * 72 + 32 + quad * 8];
#pragma unroll
            for (int m = 0; m < 2; m++) {
                s[m][nt] = __builtin_amdgcn_mfma_f32_16x16x32_bf16(qf[m][0], b0, s[m][nt], 0, 0, 0);
                s[m][nt] = __builtin_amdgcn_mfma_f32_16x16x32_bf16(qf[m][1], b1, s[m][nt], 0, 0, 0);
            }
        }

        // --- softmax numerator -> per-wave P tile ---
#pragma unroll
        for (int m = 0; m < 2; m++)
#pragma unroll
            for (int nt = 0; nt < 4; nt++) {
                float p0 = fast_exp2(s[m][nt][0]);
                float p1 = fast_exp2(s[m][nt][1]);
                float p2 = fast_exp2(s[m][nt][2]);
                float p3 = fast_exp2(s[m][nt][3]);
                l_part[m][0] += p0; l_part[m][1] += p1;
                l_part[m][2] += p2; l_part[m][3] += p3;
                unsigned int u01 = pk_bf16(p0, p1);
                unsigned int u23 = pk_bf16(p2, p3);
                const int rb   = m * 16 + quad * 4;
                const int colo = nt * 16 + l15;
                sPw[(rb + 0) * PST + colo] = (u16)(u01 & 0xFFFFu);
                sPw[(rb + 1) * PST + colo] = (u16)(u01 >> 16);
                sPw[(rb + 2) * PST + colo] = (u16)(u23 & 0xFFFFu);
                sPw[(rb + 3) * PST + colo] = (u16)(u23 >> 16);
            }

        // --- PV from sV[cur] (P is per-wave: no barrier needed) ---
#pragma unroll
        for (int c = 0; c < 2; c++) {
            bf16x8 pf0 = *(const bf16x8*)&sPw[(0 * 16 + l15) * PST + c * 32 + quad * 8];
            bf16x8 pf1 = *(const bf16x8*)&sPw[(1 * 16 + l15) * PST + c * 32 + quad * 8];
#pragma unroll
            for (int nt = 0; nt < 4; nt++) {
                bf16x8 vf = *(const bf16x8*)&sV[cur][(nt * 16 + l15) * 72 + c * 32 + quad * 8];
                oacc[0][nt] = __builtin_amdgcn_mfma_f32_16x16x32_bf16(pf0, vf, oacc[0][nt], 0, 0, 0);
                oacc[1][nt] = __builtin_amdgcn_mfma_f32_16x16x32_bf16(pf1, vf, oacc[1][nt], 0, 0, 0);
            }
        }

        // --- stage next tile into the other buffer; single barrier ---
        if (has_next) {
            const int nxt = cur ^ 1;
            *(uint4*)&sK[nxt][srow * 72 + scol]     = nkv0;
            *(uint4*)&sK[nxt][srow * 72 + scol + 8] = nkv1;
            *(uint4*)&sV[nxt][srow * 72 + scol]     = nvv0;
            *(uint4*)&sV[nxt][srow * 72 + scol + 8] = nvv1;
        }
        __syncthreads();
        cur ^= 1;
    }

#pragma unroll
    for (int m = 0; m < 2; m++) {
        float l_i[4];
#pragma unroll
        for (int r = 0; r < 4; r++) {
            float l = l_part[m][r];
            l += __shfl_xor(l, 1);
            l += __shfl_xor(l, 2);
            l += __shfl_xor(l, 4);
            l += __shfl_xor(l, 8);
            l_i[r] = l;
        }
#pragma unroll
        for (int nt = 0; nt < 4; nt++) {
            int col = head * DK + nt * 16 + l15;
#pragma unroll
            for (int r = 0; r < 4; r++) {
                int row = q0 + wave * 32 + m * 16 + quad * 4 + r;
                float o = oacc[m][nt][r] / l_i[r];
                u16 h = f2bf(o);
                AOh[(size_t)row * DMODEL + col] = h;
                AOl[(size_t)row * DMODEL + col] = f2bf(o - bf2f(h));
            }
        }
    }
}

// ---------------------------------------------------------------------------
extern "C" void kernel_launch(void* const* d_in, const int* in_sizes, int n_in,
                              void* d_out, int out_size, void* d_ws, size_t ws_size,
                              hipStream_t stream) {
    const float* query = (const float*)d_in[0];
    const float* key_t = (const float*)d_in[1];
    const float* value = (const float*)d_in[2];
    const float* wq    = (const float*)d_in[3];
    const float* wk    = (const float*)d_in[4];
    const float* wv    = (const float*)d_in[5];
    const float* wo    = (const float*)d_in[6];
    float* out = (float*)d_out;

    const size_t ACT_N = (size_t)SEQ * DMODEL;
    const size_t W_N   = (size_t)DMODEL * DMODEL;
    const size_t NEED  = 4 * ACT_N * sizeof(float);   // 64 MB (verified available)

    if (d_ws == nullptr || ws_size < NEED) {
        fallback_marker<<<dim3((out_size + 255) / 256), dim3(256), 0, stream>>>(out, out_size);
        return;
    }

    u16* ACT_HI = (u16*)d_ws;          // 8 MB  (phased)
    u16* ACT_LO = ACT_HI + ACT_N;      // 8 MB
    u16* W_HI   = ACT_LO + ACT_N;      // 2 MB  (phased)
    u16* W_LO   = W_HI + W_N;          // 2 MB
    u16* Qb     = W_LO + W_N;          // 8 MB  bf16 Q (pre-scaled 1/8*log2e)
    u16* Kb     = Qb + ACT_N;          // 8 MB  bf16 K
    u16* Vt     = Kb + ACT_N;          // 8 MB  bf16 V^T [DMODEL][SEQ]
    u16* AO_HI  = Vt + ACT_N;          // 8 MB
    u16* AO_LO  = AO_HI + ACT_N;       // 8 MB

    const int ACT4 = (int)(ACT_N / 4);
    const int W4   = (int)(W_N / 4);
    dim3 blk(256);
    dim3 pairg((ACT4 + 255) / 256, 2);
    dim3 wg((W4 + 255) / 256);

    const float QSCALE = 0.125f * 1.44269504f;   // 1/sqrt(dk) * log2(e)

    split_pair<<<pairg, blk, 0, stream>>>(query, ACT_HI, ACT_LO, ACT4, wq, W_HI, W_LO, W4);
    proj_hl_bf<<<dim3(SEQ / 128, DMODEL / 64), blk, 0, stream>>>(
        ACT_HI, ACT_LO, W_HI, W_LO, Qb, DMODEL, QSCALE);

    split_pair<<<pairg, blk, 0, stream>>>(key_t, ACT_HI, ACT_LO, ACT4, wk, W_HI, W_LO, W4);
    proj_hl_bf<<<dim3(SEQ / 128, DMODEL / 64), blk, 0, stream>>>(
        ACT_HI, ACT_LO, W_HI, W_LO, Kb, DMODEL, 1.0f);

    split_pair<<<pairg, blk, 0, stream>>>(value, ACT_HI, ACT_LO, ACT4, wv, W_HI, W_LO, W4);
    proj_hl_bf<<<dim3(DMODEL / 128, SEQ / 64), blk, 0, stream>>>(
        W_HI, W_LO, ACT_HI, ACT_LO, Vt, SEQ, 1.0f);

    attn_mfma<<<dim3(SEQ / 128, NHEAD), blk, 0, stream>>>(Qb, Kb, Vt, AO_HI, AO_LO);

    split_kernel<<<wg, blk, 0, stream>>>(wo, W_HI, W_LO, W4);
    proj_hl_f32<<<dim3(SEQ / 128, DMODEL / 64), blk, 0, stream>>>(
        AO_HI, AO_LO, W_HI, W_LO, out);
}